// Round 14
// baseline (1190.630 us; speedup 1.0000x reference)
//
#include <hip/hip_runtime.h>
#include <math.h>

// GIN 2-layer, round 14: LDS-accumulate gather (no per-node CSR sort).
//  prep -> bucket_scatter (bucket staging) -> agg_bucket (LDS acc + gemm1 input)
//  -> gemm1_mfma -> gemm2_mfma (fp8 t, 40B rows) -> final_bucket (LDS acc + softmax)
//  bucket_csr / off2 / esrc eliminated.

#define IN_DIM 64
#define HID_DIM 128
#define OUT_DIM 40

#define BSH 8
#define MAXNB 512
#define EPB 4096
#define CAP 5120      // per-bucket staging capacity (mean 4096 -> +16 sigma)

typedef unsigned short ushort;
typedef unsigned char uchar;
typedef unsigned int uint;
typedef float floatx2 __attribute__((ext_vector_type(2)));
typedef short short8_t __attribute__((ext_vector_type(8)));   // 8 bf16 (4 VGPRs)
typedef float float4_t __attribute__((ext_vector_type(4)));   // MFMA acc

__device__ __forceinline__ ushort f2bf(float f) {
  unsigned u = __float_as_uint(f);
  u += 0x7fffu + ((u >> 16) & 1u);
  return (ushort)(u >> 16);
}

// ------- prep: x -> fp8 x8 (64B rows), W1T/W2T bf16 transpose, gcur = 0 -------

__global__ __launch_bounds__(256) void prep(
    const float4* __restrict__ x4, uint2* __restrict__ x8, int n8,
    const float* __restrict__ W1, const float* __restrict__ W2,
    ushort* __restrict__ W1T, ushort* __restrict__ W2T, int* __restrict__ gcur) {
  int id = blockIdx.x * 256 + threadIdx.x;
  if (id < n8) {
    float4 a = x4[2 * id], b = x4[2 * id + 1];
    int p0 = __builtin_amdgcn_cvt_pk_fp8_f32(a.x, a.y, 0, false);
    p0 = __builtin_amdgcn_cvt_pk_fp8_f32(a.z, a.w, p0, true);
    int p1 = __builtin_amdgcn_cvt_pk_fp8_f32(b.x, b.y, 0, false);
    p1 = __builtin_amdgcn_cvt_pk_fp8_f32(b.z, b.w, p1, true);
    x8[id] = (uint2){(uint)p0, (uint)p1};
  }
  if (id < HID_DIM * IN_DIM) {             // 8192
    int c = id / IN_DIM, k = id - c * IN_DIM;
    W1T[id] = f2bf(W1[k * HID_DIM + c]);
  }
  if (id < 48 * HID_DIM) {                 // 6144
    int c = id / HID_DIM, k = id - c * HID_DIM;
    W2T[id] = (c < OUT_DIM) ? f2bf(W2[k * OUT_DIM + c]) : 0;
  }
  if (id < MAXNB) gcur[id] = 0;
}

// ---------------- CSR-lite: scatter into fixed-cap bucket staging ----------------

__global__ __launch_bounds__(256) void bucket_scatter(
    const int* __restrict__ src, const int* __restrict__ dst,
    int* __restrict__ gcur, int* __restrict__ epk_s, int n_edges, int nb) {
  __shared__ int hist[MAXNB];
  __shared__ int lexcl[MAXNB];
  __shared__ int lofs[MAXNB];
  __shared__ int gbase[MAXNB];
  __shared__ int spk[EPB];
  __shared__ ushort sbid[EPB];
  int tid = threadIdx.x;
  for (int i = tid; i < nb; i += 256) { hist[i] = 0; lofs[i] = 0; }
  __syncthreads();
  int e0 = blockIdx.x * EPB;
  int cnt = min(EPB, n_edges - e0);
  for (int i = tid; i < cnt; i += 256) atomicAdd(&hist[dst[e0 + i] >> BSH], 1);
  __syncthreads();
  if (tid < 64) {  // wave-0 exclusive scan
    int carry = 0;
    for (int c = 0; c < nb; c += 64) {
      int v = (c + tid < nb) ? hist[c + tid] : 0;
      int incl = v;
#pragma unroll
      for (int d = 1; d < 64; d <<= 1) {
        int t = __shfl_up(incl, d, 64);
        if (tid >= d) incl += t;
      }
      if (c + tid < nb) lexcl[c + tid] = carry + incl - v;
      carry += __shfl(incl, 63, 64);
    }
  }
  __syncthreads();
  for (int i = tid; i < nb; i += 256)
    if (hist[i]) gbase[i] = atomicAdd(&gcur[i], hist[i]);
  __syncthreads();
  for (int i = tid; i < cnt; i += 256) {
    int d = dst[e0 + i], s = src[e0 + i];
    int b = d >> BSH;
    int p = lexcl[b] + atomicAdd(&lofs[b], 1);
    spk[p] = ((d & 255) << 17) | s;      // n_nodes < 2^17
    sbid[p] = (ushort)b;
  }
  __syncthreads();
  for (int i = tid; i < cnt; i += 256) {  // copy-out (bucket-grouped -> coalesced runs)
    int b = sbid[i];
    epk_s[b * CAP + gbase[b] + (i - lexcl[b])] = spk[i];
  }
}

// -------- agg_bucket: one block per bucket; LDS acc[256][64] fp32, rotated cols --------
// aggrh[n] = bf16(x[n] + sum_{edges dst=n} x8[src]); edges consumed unsorted.

__global__ __launch_bounds__(256) void agg_bucket(
    const float4* __restrict__ x4, const uint* __restrict__ x8,
    const int* __restrict__ epk_s, const int* __restrict__ gcnt,
    ushort* __restrict__ aggrh, int n_nodes) {
  __shared__ float acc[256 * 64];   // 64 KB
  int tid = threadIdx.x;
  int b = blockIdx.x;
  int base = b * CAP;
  int cnt = gcnt[b];
  int nb0 = b << BSH;
  for (int i = tid; i < 256 * 64; i += 256) acc[i] = 0.f;
  __syncthreads();
  int wid = tid >> 6;
  int es = (tid >> 4) & 3, q = tid & 15;
  for (int i = wid * 4; i < cnt; i += 16) {
    int idx = i + es;
    if (idx < cnt) {
      int p = epk_s[base + idx];
      int s = p & 0x1FFFF, d = p >> 17;
      uint u = x8[(uint)(s * 16 + q)];
      floatx2 lo = __builtin_amdgcn_cvt_pk_f32_fp8((int)u, false);
      floatx2 hi = __builtin_amdgcn_cvt_pk_f32_fp8((int)u, true);
      int f0 = 4 * q + d;   // rotated column (bank spread)
      atomicAdd(&acc[d * 64 + (f0 & 63)], lo[0]);
      atomicAdd(&acc[d * 64 + ((f0 + 1) & 63)], lo[1]);
      atomicAdd(&acc[d * 64 + ((f0 + 2) & 63)], hi[0]);
      atomicAdd(&acc[d * 64 + ((f0 + 3) & 63)], hi[1]);
    }
  }
  __syncthreads();
  // writeout: 16 nodes per pass, thread (nl = tid>>4, qq = tid&15)
  int nl = tid >> 4, qq = tid & 15;
#pragma unroll
  for (int it = 0; it < 16; ++it) {
    int nn = it * 16 + nl;
    int node = nb0 + nn;
    if (node < n_nodes) {
      float4 xo = x4[(uint)(node * 16 + qq)];
      int f0 = 4 * qq + nn;
      float a0 = acc[nn * 64 + (f0 & 63)] + xo.x;
      float a1 = acc[nn * 64 + ((f0 + 1) & 63)] + xo.y;
      float a2 = acc[nn * 64 + ((f0 + 2) & 63)] + xo.z;
      float a3 = acc[nn * 64 + ((f0 + 3) & 63)] + xo.w;
      uint2 o;
      o.x = (uint)f2bf(a0) | ((uint)f2bf(a1) << 16);
      o.y = (uint)f2bf(a2) | ((uint)f2bf(a3) << 16);
      ((uint2*)aggrh)[(uint)(node * 16 + qq)] = o;
    }
  }
}

// ------- gemm1 (MFMA): h1h = bf16(relu(aggr @ W1 + b1)) -------

__global__ __launch_bounds__(256) void gemm1_mfma(
    const ushort* __restrict__ aggrh, const ushort* __restrict__ W1T,
    const float* __restrict__ b1, ushort* __restrict__ h1h, int n_nodes) {
  int w = threadIdx.x >> 6, lane = threadIdx.x & 63;
  int n0 = blockIdx.x * 64 + w * 16;
  int row = lane & 15, kg = lane >> 4;
  int n = n0 + row;
  short8_t a0 = {}, a1 = {};
  if (n < n_nodes) {
    a0 = *(const short8_t*)&aggrh[(size_t)n * IN_DIM + kg * 8];
    a1 = *(const short8_t*)&aggrh[(size_t)n * IN_DIM + 32 + kg * 8];
  }
  float4_t acc[8];
#pragma unroll
  for (int ct = 0; ct < 8; ++ct) acc[ct] = (float4_t){0.f, 0.f, 0.f, 0.f};
#pragma unroll
  for (int ct = 0; ct < 8; ++ct) {
    int c = ct * 16 + row;
    short8_t b0 = *(const short8_t*)&W1T[(size_t)c * IN_DIM + kg * 8];
    short8_t b1f = *(const short8_t*)&W1T[(size_t)c * IN_DIM + 32 + kg * 8];
    acc[ct] = __builtin_amdgcn_mfma_f32_16x16x32_bf16(a0, b0, acc[ct], 0, 0, 0);
    acc[ct] = __builtin_amdgcn_mfma_f32_16x16x32_bf16(a1, b1f, acc[ct], 0, 0, 0);
  }
#pragma unroll
  for (int ct = 0; ct < 8; ++ct) {
    int j = ct * 16 + row;
    float bias = b1[j];
#pragma unroll
    for (int i = 0; i < 4; ++i) {
      int nn = n0 + kg * 4 + i;
      if (nn < n_nodes)
        h1h[(size_t)nn * HID_DIM + j] = f2bf(fmaxf(acc[ct][i] + bias, 0.f));
    }
  }
}

// ------- gemm2 (MFMA): th8 = fp8(h1 @ W2), row stride 40 B -------

__global__ __launch_bounds__(256) void gemm2_mfma(
    const ushort* __restrict__ h1h, const ushort* __restrict__ W2T,
    uchar* __restrict__ th8, int n_nodes) {
  int w = threadIdx.x >> 6, lane = threadIdx.x & 63;
  int n0 = blockIdx.x * 64 + w * 16;
  int row = lane & 15, kg = lane >> 4;
  int n = n0 + row;
  short8_t a[4] = {};
  if (n < n_nodes) {
#pragma unroll
    for (int ks = 0; ks < 4; ++ks)
      a[ks] = *(const short8_t*)&h1h[(size_t)n * HID_DIM + ks * 32 + kg * 8];
  }
  float4_t acc[3];
#pragma unroll
  for (int ct = 0; ct < 3; ++ct) acc[ct] = (float4_t){0.f, 0.f, 0.f, 0.f};
#pragma unroll
  for (int ct = 0; ct < 3; ++ct) {
    int c = ct * 16 + row;
#pragma unroll
    for (int ks = 0; ks < 4; ++ks) {
      short8_t b = *(const short8_t*)&W2T[(size_t)c * HID_DIM + ks * 32 + kg * 8];
      acc[ct] = __builtin_amdgcn_mfma_f32_16x16x32_bf16(a[ks], b, acc[ct], 0, 0, 0);
    }
  }
#pragma unroll
  for (int ct = 0; ct < 3; ++ct) {
    int j = ct * 16 + row;
    if (j < OUT_DIM) {
#pragma unroll
      for (int i = 0; i < 4; ++i) {
        int nn = n0 + kg * 4 + i;
        if (nn < n_nodes) {
          int pk = __builtin_amdgcn_cvt_pk_fp8_f32(acc[ct][i], acc[ct][i], 0, false);
          th8[(size_t)nn * 40 + j] = (uchar)(pk & 0xff);
        }
      }
    }
  }
}

// -------- final_bucket: one block per bucket; LDS acc[256][44]; serial softmax --------
// out[n] = log_softmax(t[n] + sum_{edges dst=n} t[src] + b2)

__global__ __launch_bounds__(256) void final_bucket(
    const uchar* __restrict__ th8, const int* __restrict__ epk_s,
    const int* __restrict__ gcnt, const float* __restrict__ b2,
    float* __restrict__ out, int n_nodes) {
  __shared__ float acc[256 * 44];   // 44 KB (stride 44 for bank spread)
  int tid = threadIdx.x;
  int b = blockIdx.x;
  int base = b * CAP;
  int cnt = gcnt[b];
  int nb0 = b << BSH;
  const uint* tr = (const uint*)th8;   // row = 10 uints (40 B)
  for (int i = tid; i < 256 * 44; i += 256) acc[i] = 0.f;
  __syncthreads();
  int wid = tid >> 6, lane = tid & 63;
  int es = lane / 10, q = lane - es * 10;   // es 0..6 (es==6 -> idle lane)
  for (int i = wid * 6; i < cnt; i += 24) {
    int idx = i + es;
    if (es < 6 && idx < cnt) {
      int p = epk_s[base + idx];
      int s = p & 0x1FFFF, d = p >> 17;
      uint u = tr[(uint)(s * 10 + q)];
      floatx2 lo = __builtin_amdgcn_cvt_pk_f32_fp8((int)u, false);
      floatx2 hi = __builtin_amdgcn_cvt_pk_f32_fp8((int)u, true);
      float* ap = &acc[d * 44 + 4 * q];
      atomicAdd(ap + 0, lo[0]);
      atomicAdd(ap + 1, lo[1]);
      atomicAdd(ap + 2, hi[0]);
      atomicAdd(ap + 3, hi[1]);
    }
  }
  __syncthreads();
  // one node per thread: own row + bias, serial softmax over 40 feats
  int node = nb0 + tid;
  if (node >= n_nodes) return;
  float z[40];
#pragma unroll
  for (int j = 0; j < 10; ++j) {
    uint u = tr[(uint)(node * 10 + j)];
    floatx2 lo = __builtin_amdgcn_cvt_pk_f32_fp8((int)u, false);
    floatx2 hi = __builtin_amdgcn_cvt_pk_f32_fp8((int)u, true);
    z[4 * j + 0] = acc[tid * 44 + 4 * j + 0] + lo[0] + b2[4 * j + 0];
    z[4 * j + 1] = acc[tid * 44 + 4 * j + 1] + lo[1] + b2[4 * j + 1];
    z[4 * j + 2] = acc[tid * 44 + 4 * j + 2] + hi[0] + b2[4 * j + 2];
    z[4 * j + 3] = acc[tid * 44 + 4 * j + 3] + hi[1] + b2[4 * j + 3];
  }
  float m = z[0];
#pragma unroll
  for (int f = 1; f < 40; ++f) m = fmaxf(m, z[f]);
  float ssum = 0.f;
#pragma unroll
  for (int f = 0; f < 40; ++f) ssum += __expf(z[f] - m);
  float ls = m + __logf(ssum);
  float4* op = (float4*)&out[(size_t)node * 40];
#pragma unroll
  for (int j = 0; j < 10; ++j) {
    float4 o = {z[4 * j] - ls, z[4 * j + 1] - ls, z[4 * j + 2] - ls, z[4 * j + 3] - ls};
    op[j] = o;
  }
}

// ---------------- launch ----------------

static inline char* align256(char* p) {
  return (char*)(((uintptr_t)p + 255) & ~(uintptr_t)255);
}

extern "C" void kernel_launch(void* const* d_in, const int* in_sizes, int n_in,
                              void* d_out, int out_size, void* d_ws, size_t ws_size,
                              hipStream_t stream) {
  const float* x  = (const float*)d_in[0];
  const int*   ei = (const int*)d_in[1];    // [2][E] int32
  const float* W1 = (const float*)d_in[2];
  const float* b1 = (const float*)d_in[3];
  const float* W2 = (const float*)d_in[4];
  const float* b2 = (const float*)d_in[5];
  float* out = (float*)d_out;

  int n_nodes = in_sizes[0] / IN_DIM;
  int n_edges = in_sizes[1] / 2;
  const int* src = ei;
  const int* dst = ei + n_edges;
  int nb = (n_nodes + 255) >> BSH;

  char* p = (char*)d_ws;
  int* gcur   = (int*)p;            p += MAXNB * 4;
  p = align256(p);
  int* epk_s  = (int*)p;            p += (size_t)nb * CAP * 4;
  p = align256(p);
  uchar* x8    = (uchar*)p;         p += (size_t)n_nodes * IN_DIM;      // fp8, 64 B rows
  p = align256(p);
  ushort* aggrh = (ushort*)p;       p += (size_t)n_nodes * IN_DIM * 2;
  p = align256(p);
  ushort* h1h   = (ushort*)p;       p += (size_t)n_nodes * HID_DIM * 2;
  p = align256(p);
  uchar* th8    = (uchar*)p;        p += (size_t)n_nodes * 40 + 256;    // fp8, 40 B rows
  p = align256(p);
  ushort* W1T   = (ushort*)p;       p += HID_DIM * IN_DIM * 2;          // [128][64]
  ushort* W2T   = (ushort*)p;       p += 48 * HID_DIM * 2;              // [48][128]

  int n8 = n_nodes * IN_DIM / 8;
  prep<<<(n8 + 255) / 256, 256, 0, stream>>>(
      (const float4*)x, (uint2*)x8, n8, W1, W2, W1T, W2T, gcur);

  int egrid = (n_edges + EPB - 1) / EPB;
  bucket_scatter<<<egrid, 256, 0, stream>>>(src, dst, gcur, epk_s, n_edges, nb);

  agg_bucket<<<nb, 256, 0, stream>>>(
      (const float4*)x, (const uint*)x8, epk_s, gcur, aggrh, n_nodes);
  int ggrid = (n_nodes + 63) / 64;
  gemm1_mfma<<<ggrid, 256, 0, stream>>>(aggrh, W1T, b1, h1h, n_nodes);
  gemm2_mfma<<<ggrid, 256, 0, stream>>>(h1h, W2T, th8, n_nodes);
  final_bucket<<<nb, 256, 0, stream>>>(th8, epk_s, gcur, b2, out, n_nodes);
}

// Round 15
// 148.627 us; speedup vs baseline: 8.0109x; 8.0109x over previous
//
#include <hip/hip_runtime.h>
#include <math.h>

// GIN 2-layer, round 15: R13 structure (revert of failed R14 LDS-atomic experiment)
// + gemm1/gemm2 fused into one kernel with h1 staged in LDS (no h1h HBM round-trip).
//  prep -> bucket_scatter -> bucket_csr -> agg1 -> gemm12 -> final_fused

#define IN_DIM 64
#define HID_DIM 128
#define OUT_DIM 40

#define BSH 8
#define MAXNB 512
#define EPB 4096
#define CAP 5120      // per-bucket staging capacity (mean 4096 -> +16 sigma)
#define H1S 136       // LDS h1 row stride in bf16 (16B-aligned, bank-spread)

typedef unsigned short ushort;
typedef unsigned char uchar;
typedef unsigned int uint;
typedef float floatx2 __attribute__((ext_vector_type(2)));
typedef short short8_t __attribute__((ext_vector_type(8)));   // 8 bf16 (4 VGPRs)
typedef float float4_t __attribute__((ext_vector_type(4)));   // MFMA acc

__device__ __forceinline__ ushort f2bf(float f) {
  unsigned u = __float_as_uint(f);
  u += 0x7fffu + ((u >> 16) & 1u);
  return (ushort)(u >> 16);
}

// ------- prep: x -> fp8 x8 (64B rows), W1T/W2T bf16 transpose, gcur = 0 -------

__global__ __launch_bounds__(256) void prep(
    const float4* __restrict__ x4, uint2* __restrict__ x8, int n8,
    const float* __restrict__ W1, const float* __restrict__ W2,
    ushort* __restrict__ W1T, ushort* __restrict__ W2T, int* __restrict__ gcur) {
  int id = blockIdx.x * 256 + threadIdx.x;
  if (id < n8) {
    float4 a = x4[2 * id], b = x4[2 * id + 1];
    int p0 = __builtin_amdgcn_cvt_pk_fp8_f32(a.x, a.y, 0, false);
    p0 = __builtin_amdgcn_cvt_pk_fp8_f32(a.z, a.w, p0, true);
    int p1 = __builtin_amdgcn_cvt_pk_fp8_f32(b.x, b.y, 0, false);
    p1 = __builtin_amdgcn_cvt_pk_fp8_f32(b.z, b.w, p1, true);
    x8[id] = (uint2){(uint)p0, (uint)p1};
  }
  if (id < HID_DIM * IN_DIM) {             // 8192
    int c = id / IN_DIM, k = id - c * IN_DIM;
    W1T[id] = f2bf(W1[k * HID_DIM + c]);
  }
  if (id < 48 * HID_DIM) {                 // 6144
    int c = id / HID_DIM, k = id - c * HID_DIM;
    W2T[id] = (c < OUT_DIM) ? f2bf(W2[k * OUT_DIM + c]) : 0;
  }
  if (id < MAXNB) gcur[id] = 0;
}

// ---------------- CSR build: scatter into fixed-cap bucket staging ----------------

__global__ __launch_bounds__(256) void bucket_scatter(
    const int* __restrict__ src, const int* __restrict__ dst,
    int* __restrict__ gcur, int* __restrict__ epk_s, int n_edges, int nb) {
  __shared__ int hist[MAXNB];
  __shared__ int lexcl[MAXNB];
  __shared__ int lofs[MAXNB];
  __shared__ int gbase[MAXNB];
  __shared__ int spk[EPB];
  __shared__ ushort sbid[EPB];
  int tid = threadIdx.x;
  for (int i = tid; i < nb; i += 256) { hist[i] = 0; lofs[i] = 0; }
  __syncthreads();
  int e0 = blockIdx.x * EPB;
  int cnt = min(EPB, n_edges - e0);
  for (int i = tid; i < cnt; i += 256) atomicAdd(&hist[dst[e0 + i] >> BSH], 1);
  __syncthreads();
  if (tid < 64) {  // wave-0 exclusive scan
    int carry = 0;
    for (int c = 0; c < nb; c += 64) {
      int v = (c + tid < nb) ? hist[c + tid] : 0;
      int incl = v;
#pragma unroll
      for (int d = 1; d < 64; d <<= 1) {
        int t = __shfl_up(incl, d, 64);
        if (tid >= d) incl += t;
      }
      if (c + tid < nb) lexcl[c + tid] = carry + incl - v;
      carry += __shfl(incl, 63, 64);
    }
  }
  __syncthreads();
  for (int i = tid; i < nb; i += 256)
    if (hist[i]) gbase[i] = atomicAdd(&gcur[i], hist[i]);
  __syncthreads();
  for (int i = tid; i < cnt; i += 256) {
    int d = dst[e0 + i], s = src[e0 + i];
    int b = d >> BSH;
    int p = lexcl[b] + atomicAdd(&lofs[b], 1);
    spk[p] = ((d & 255) << 17) | s;      // n_nodes < 2^17
    sbid[p] = (ushort)b;
  }
  __syncthreads();
  for (int i = tid; i < cnt; i += 256) {  // copy-out into staging
    int b = sbid[i];
    epk_s[b * CAP + gbase[b] + (i - lexcl[b])] = spk[i];
  }
}

// ------- bucket_csr: per-bucket node hist/scan -> off2{start,end} + sorted esrc -------

__global__ __launch_bounds__(256) void bucket_csr(
    const int* __restrict__ epk_s, const int* __restrict__ gcnt,
    int2* __restrict__ off2, int* __restrict__ esrc_s, int n_nodes) {
  __shared__ int hist[256];
  __shared__ int cur[256];
  int b = blockIdx.x;
  int base = b * CAP;
  int cnt = gcnt[b];
  int nb0 = b << BSH;
  int nn = min(256, n_nodes - nb0);
  int tid = threadIdx.x;
  hist[tid] = 0;
  __syncthreads();
  for (int i = tid; i < cnt; i += 256) atomicAdd(&hist[epk_s[base + i] >> 17], 1);
  __syncthreads();
  if (tid < 64) {  // exclusive scan of 256 entries
    int carry = 0;
#pragma unroll
    for (int c = 0; c < 256; c += 64) {
      int v = hist[c + tid];
      int incl = v;
#pragma unroll
      for (int d = 1; d < 64; d <<= 1) {
        int t = __shfl_up(incl, d, 64);
        if (tid >= d) incl += t;
      }
      cur[c + tid] = carry + incl - v;
      carry += __shfl(incl, 63, 64);
    }
  }
  __syncthreads();
  if (tid < nn) {
    int st = cur[tid];
    off2[nb0 + tid] = make_int2(base + st, base + st + hist[tid]);
  }
  __syncthreads();  // off2 reads cur/hist before scatter mutates cur
  for (int i = tid; i < cnt; i += 256) {
    int p = epk_s[base + i];
    int pos = atomicAdd(&cur[p >> 17], 1);
    esrc_s[base + pos] = p & 0x1FFFF;
  }
}

// -------- agg1: aggr1h[n] = bf16(x[n] + sum_j x8[j]), 2 nodes/wave --------
// lane: bit5 = node-select, bit4 = edge-slot, bits0-3 = dword q of 64B row.

__global__ __launch_bounds__(256) void agg1(
    const float4* __restrict__ x4, const uint* __restrict__ x8,
    const int2* __restrict__ off2, const int* __restrict__ esrc,
    ushort* __restrict__ aggrh, int n_nodes) {
  int tid = threadIdx.x;
  int lane = tid & 63;
  int nsel = (lane >> 5) & 1, es = (lane >> 4) & 1, q = lane & 15;
  int node = blockIdx.x * 8 + (tid >> 6) * 2 + nsel;
  bool nok = node < n_nodes;
  int2 oe = nok ? off2[node] : make_int2(0, 0);
  float4 xo = nok ? x4[(uint)(node * 16 + q)] : (float4){0.f, 0.f, 0.f, 0.f};
  floatx2 A0 = {0.f, 0.f}, A1 = {0.f, 0.f};
  floatx2 C0 = {0.f, 0.f}, C1 = {0.f, 0.f};
  int e = oe.x, end = oe.y;
  for (; e + 4 <= end; e += 4) {
    uint u0 = x8[(uint)(esrc[e + es] * 16 + q)];
    uint u1 = x8[(uint)(esrc[e + es + 2] * 16 + q)];
    A0 += __builtin_amdgcn_cvt_pk_f32_fp8((int)u0, false);
    A1 += __builtin_amdgcn_cvt_pk_f32_fp8((int)u0, true);
    C0 += __builtin_amdgcn_cvt_pk_f32_fp8((int)u1, false);
    C1 += __builtin_amdgcn_cvt_pk_f32_fp8((int)u1, true);
  }
  for (; e < end; e += 2) {
    int idx = e + es;
    if (idx < end) {
      uint u = x8[(uint)(esrc[idx] * 16 + q)];
      A0 += __builtin_amdgcn_cvt_pk_f32_fp8((int)u, false);
      A1 += __builtin_amdgcn_cvt_pk_f32_fp8((int)u, true);
    }
  }
  A0 += C0; A1 += C1;
  {  // reduce over edge-slot bit 4
    floatx2 t0, t1;
    t0[0] = __shfl_xor(A0[0], 16, 64); t0[1] = __shfl_xor(A0[1], 16, 64);
    t1[0] = __shfl_xor(A1[0], 16, 64); t1[1] = __shfl_xor(A1[1], 16, 64);
    A0 += t0; A1 += t1;
  }
  A0 += (floatx2){xo.x, xo.y};
  A1 += (floatx2){xo.z, xo.w};
  if (nok && es == 0) {
    uint2 o;
    o.x = (uint)f2bf(A0[0]) | ((uint)f2bf(A0[1]) << 16);
    o.y = (uint)f2bf(A1[0]) | ((uint)f2bf(A1[1]) << 16);
    ((uint2*)aggrh)[(uint)(node * 16 + q)] = o;
  }
}

// ------- gemm12 (MFMA, fused): th8 = fp8((relu(aggr@W1+b1)) @ W2), h1 in LDS -------
// 64 nodes/block, 4 waves x 16 nodes. h1s[64][H1S] bf16 (17.4 KB).

__global__ __launch_bounds__(256) void gemm12_mfma(
    const ushort* __restrict__ aggrh, const ushort* __restrict__ W1T,
    const float* __restrict__ b1, const ushort* __restrict__ W2T,
    uchar* __restrict__ th8, int n_nodes) {
  __shared__ ushort h1s[64 * H1S];
  int w = threadIdx.x >> 6, lane = threadIdx.x & 63;
  int n0 = blockIdx.x * 64 + w * 16;
  int row = lane & 15, kg = lane >> 4;
  int n = n0 + row;
  // ---- layer 1 ----
  {
    short8_t a0 = {}, a1 = {};
    if (n < n_nodes) {
      a0 = *(const short8_t*)&aggrh[(size_t)n * IN_DIM + kg * 8];
      a1 = *(const short8_t*)&aggrh[(size_t)n * IN_DIM + 32 + kg * 8];
    }
    float4_t acc[8];
#pragma unroll
    for (int ct = 0; ct < 8; ++ct) acc[ct] = (float4_t){0.f, 0.f, 0.f, 0.f};
#pragma unroll
    for (int ct = 0; ct < 8; ++ct) {
      int c = ct * 16 + row;
      short8_t b0 = *(const short8_t*)&W1T[(size_t)c * IN_DIM + kg * 8];
      short8_t b1f = *(const short8_t*)&W1T[(size_t)c * IN_DIM + 32 + kg * 8];
      acc[ct] = __builtin_amdgcn_mfma_f32_16x16x32_bf16(a0, b0, acc[ct], 0, 0, 0);
      acc[ct] = __builtin_amdgcn_mfma_f32_16x16x32_bf16(a1, b1f, acc[ct], 0, 0, 0);
    }
#pragma unroll
    for (int ct = 0; ct < 8; ++ct) {
      int j = ct * 16 + row;
      float bias = b1[j];
#pragma unroll
      for (int i = 0; i < 4; ++i) {
        int nl = w * 16 + kg * 4 + i;   // local node index 0..63
        h1s[nl * H1S + j] = f2bf(fmaxf(acc[ct][i] + bias, 0.f));
      }
    }
  }
  __syncthreads();
  // ---- layer 2 (A-fragments from LDS) ----
  {
    short8_t a[4];
#pragma unroll
    for (int ks = 0; ks < 4; ++ks)
      a[ks] = *(const short8_t*)&h1s[(w * 16 + row) * H1S + ks * 32 + kg * 8];
    float4_t acc[3];
#pragma unroll
    for (int ct = 0; ct < 3; ++ct) acc[ct] = (float4_t){0.f, 0.f, 0.f, 0.f};
#pragma unroll
    for (int ct = 0; ct < 3; ++ct) {
      int c = ct * 16 + row;
#pragma unroll
      for (int ks = 0; ks < 4; ++ks) {
        short8_t b = *(const short8_t*)&W2T[(size_t)c * HID_DIM + ks * 32 + kg * 8];
        acc[ct] = __builtin_amdgcn_mfma_f32_16x16x32_bf16(a[ks], b, acc[ct], 0, 0, 0);
      }
    }
#pragma unroll
    for (int ct = 0; ct < 3; ++ct) {
      int j = ct * 16 + row;
      if (j < OUT_DIM) {
#pragma unroll
        for (int i = 0; i < 4; ++i) {
          int nn = n0 + kg * 4 + i;
          if (nn < n_nodes) {
            int pk = __builtin_amdgcn_cvt_pk_fp8_f32(acc[ct][i], acc[ct][i], 0, false);
            th8[(size_t)nn * 40 + j] = (uchar)(pk & 0xff);
          }
        }
      }
    }
  }
}

// ------- final: out = log_softmax(t[n] + sum_j t[j] + b2), 2 nodes/wave -------
// lane: bit5 = node-select, bit4 = edge-slot, bits0-3 = dword q (valid q<10).

__global__ __launch_bounds__(256) void final_fused(
    const uchar* __restrict__ th8, const int2* __restrict__ off2,
    const int* __restrict__ esrc, const float* __restrict__ b2,
    float* __restrict__ out, int n_nodes) {
  int tid = threadIdx.x;
  int lane = tid & 63;
  int nsel = (lane >> 5) & 1, es = (lane >> 4) & 1, q = lane & 15;
  int node = blockIdx.x * 8 + (tid >> 6) * 2 + nsel;
  bool nok = node < n_nodes;
  bool valid = nok && (q < 10);
  const uint* tr = (const uint*)th8;   // row = 10 uints (40 B)
  int2 oe = nok ? off2[node] : make_int2(0, 0);
  uint uown = 0;
  float4 bb = {0.f, 0.f, 0.f, 0.f};
  if (valid) {
    uown = tr[(uint)(node * 10 + q)];
    bb = ((const float4*)b2)[q];
  }
  floatx2 A01 = {0.f, 0.f}, A23 = {0.f, 0.f};
  floatx2 C01 = {0.f, 0.f}, C23 = {0.f, 0.f};
  int e = oe.x, end = oe.y;
  for (; e + 4 <= end; e += 4) {
    uint u0 = 0, u1 = 0;
    if (valid) {
      u0 = tr[(uint)(esrc[e + es] * 10 + q)];
      u1 = tr[(uint)(esrc[e + es + 2] * 10 + q)];
    }
    A01 += __builtin_amdgcn_cvt_pk_f32_fp8((int)u0, false);
    A23 += __builtin_amdgcn_cvt_pk_f32_fp8((int)u0, true);
    C01 += __builtin_amdgcn_cvt_pk_f32_fp8((int)u1, false);
    C23 += __builtin_amdgcn_cvt_pk_f32_fp8((int)u1, true);
  }
  for (; e < end; e += 2) {
    int idx = e + es;
    if (idx < end && valid) {
      uint u = tr[(uint)(esrc[idx] * 10 + q)];
      A01 += __builtin_amdgcn_cvt_pk_f32_fp8((int)u, false);
      A23 += __builtin_amdgcn_cvt_pk_f32_fp8((int)u, true);
    }
  }
  A01 += C01; A23 += C23;
  {  // reduce over edge-slot bit 4
    floatx2 t0, t1;
    t0[0] = __shfl_xor(A01[0], 16, 64); t0[1] = __shfl_xor(A01[1], 16, 64);
    t1[0] = __shfl_xor(A23[0], 16, 64); t1[1] = __shfl_xor(A23[1], 16, 64);
    A01 += t0; A23 += t1;
  }
  // own row + bias
  A01 += __builtin_amdgcn_cvt_pk_f32_fp8((int)uown, false);
  A23 += __builtin_amdgcn_cvt_pk_f32_fp8((int)uown, true);
  A01 += (floatx2){bb.x, bb.y};
  A23 += (floatx2){bb.z, bb.w};
  // softmax over 40 feats: (q<10) x 4 regs; reduce lane bits 0-3
  float m = valid ? fmaxf(fmaxf(A01[0], A01[1]), fmaxf(A23[0], A23[1])) : -INFINITY;
#pragma unroll
  for (int d = 1; d <= 8; d <<= 1) m = fmaxf(m, __shfl_xor(m, d, 64));
  float ssum = 0.f;
  if (valid)
    ssum = (__expf(A01[0] - m) + __expf(A01[1] - m)) +
           (__expf(A23[0] - m) + __expf(A23[1] - m));
#pragma unroll
  for (int d = 1; d <= 8; d <<= 1) ssum += __shfl_xor(ssum, d, 64);
  if (valid && es == 0) {
    float ls = m + __logf(ssum);
    float4 o = {A01[0] - ls, A01[1] - ls, A23[0] - ls, A23[1] - ls};
    ((float4*)out)[(uint)(node * 10 + q)] = o;
  }
}

// ---------------- launch ----------------

static inline char* align256(char* p) {
  return (char*)(((uintptr_t)p + 255) & ~(uintptr_t)255);
}

extern "C" void kernel_launch(void* const* d_in, const int* in_sizes, int n_in,
                              void* d_out, int out_size, void* d_ws, size_t ws_size,
                              hipStream_t stream) {
  const float* x  = (const float*)d_in[0];
  const int*   ei = (const int*)d_in[1];    // [2][E] int32
  const float* W1 = (const float*)d_in[2];
  const float* b1 = (const float*)d_in[3];
  const float* W2 = (const float*)d_in[4];
  const float* b2 = (const float*)d_in[5];
  float* out = (float*)d_out;

  int n_nodes = in_sizes[0] / IN_DIM;
  int n_edges = in_sizes[1] / 2;
  const int* src = ei;
  const int* dst = ei + n_edges;
  int nb = (n_nodes + 255) >> BSH;

  char* p = (char*)d_ws;
  int* gcur   = (int*)p;            p += MAXNB * 4;
  int2* off2  = (int2*)p;           p += (size_t)n_nodes * 8;
  p = align256(p);
  int* epk_s  = (int*)p;            p += (size_t)nb * CAP * 4;
  int* esrc_s = (int*)p;            p += (size_t)nb * CAP * 4;
  p = align256(p);
  uchar* x8    = (uchar*)p;         p += (size_t)n_nodes * IN_DIM;      // fp8, 64 B rows
  p = align256(p);
  ushort* aggrh = (ushort*)p;       p += (size_t)n_nodes * IN_DIM * 2;
  p = align256(p);
  uchar* th8    = (uchar*)p;        p += (size_t)n_nodes * 40 + 256;    // fp8, 40 B rows
  p = align256(p);
  ushort* W1T   = (ushort*)p;       p += HID_DIM * IN_DIM * 2;          // [128][64]
  ushort* W2T   = (ushort*)p;       p += 48 * HID_DIM * 2;              // [48][128]

  int n8 = n_nodes * IN_DIM / 8;
  prep<<<(n8 + 255) / 256, 256, 0, stream>>>(
      (const float4*)x, (uint2*)x8, n8, W1, W2, W1T, W2T, gcur);

  int egrid = (n_edges + EPB - 1) / EPB;
  bucket_scatter<<<egrid, 256, 0, stream>>>(src, dst, gcur, epk_s, n_edges, nb);
  bucket_csr<<<nb, 256, 0, stream>>>(epk_s, gcur, off2, esrc_s, n_nodes);

  agg1<<<(n_nodes + 7) / 8, 256, 0, stream>>>(
      (const float4*)x, (const uint*)x8, off2, esrc_s, aggrh, n_nodes);
  int ggrid = (n_nodes + 63) / 64;
  gemm12_mfma<<<ggrid, 256, 0, stream>>>(aggrh, W1T, b1, W2T, th8, n_nodes);
  final_fused<<<(n_nodes + 7) / 8, 256, 0, stream>>>(th8, off2, esrc_s, b2, out, n_nodes);
}